// Round 8
// baseline (333.281 us; speedup 1.0000x reference)
//
#include <hip/hip_runtime.h>

#define N_ENT 100000
#define N_USR 30000
#define N_TOTN 130000
#define N_RELC 32
#define DIM 64
#define NEDGE 500000
#define INTER 500000
#define SLOPE 0.01f
#define CPT_NB 127     // compaction blocks: 127*1024 = 130048 >= 130000
#define FILL_NB 489    // ceil(125000/256) — 4 pairs per thread
#define RSTR 64        // fixed CSR row stride (max degree; Poisson(16.7) tail ~1e-16)
#define L1G_NB 2048    // 8 blocks/CU x 4 waves = 32 waves/CU; dynamic row pool
// k_front block layout: [0,17) m_rel | [17,19) W transpose | [19,31) r2 scatter
//                       [31,1985) kg_off | [1985,2474) mark(LDS-bitmap)
#define FR_TR 17
#define FR_R2 19
#define FR_KG 31
#define FR_MK 1985
#define FR_NB 2474

typedef unsigned char u8;
typedef unsigned int u32;
typedef unsigned long long u64;

__device__ __forceinline__ float grp_sum16(float v){
  v += __shfl_xor(v, 8, 64);
  v += __shfl_xor(v, 4, 64);
  v += __shfl_xor(v, 2, 64);
  v += __shfl_xor(v, 1, 64);
  return v;
}

// fused front: m_rel/b_rel + Wa/Wb transpose + r2 scatter + kg_off scan +
// mark (mark blocks rebuild r2 as LDS bitmaps from the 3K ids directly).
// NOTE: zero-init stays a SEPARATE prior hipMemsetAsync (R11 race).
// NOTE 2: manual grid barriers / cooperative launch are CONDEMNED on this
// stack (R1 silent no-launch; R2/R3 HSA aborts). Regular launches only.
// NOTE 3: dispatch-boundary gap measured ~3us (R6->R7 calibration) — merging
// kernels is only worth it if it also removes work or improves balance.
__global__ void __launch_bounds__(256) k_front(
    const float* __restrict__ rel, const float* __restrict__ Wk,
    const float* __restrict__ Wkb, float* __restrict__ m, float* __restrict__ b,
    const float* __restrict__ Wa, const float* __restrict__ Wb,
    float* __restrict__ wat, float* __restrict__ wbt,
    const int* __restrict__ user_ids, const int* __restrict__ item_ids,
    u8* __restrict__ r2_item, u8* __restrict__ r2_user,
    const int* __restrict__ h_list, int* __restrict__ off,
    const int4* __restrict__ a_row4, const int4* __restrict__ a_col4,
    u8* __restrict__ need_d, u8* __restrict__ need_u){
  int bid = blockIdx.x;
  int t = threadIdx.x;
  if (bid < FR_TR){
    int idx = bid*256 + t;
    if (idx < N_RELC*128){
      int r = idx >> 7, j = idx & 127;
      float s = 0.f;
      for (int d = 0; d < DIM; ++d) s += rel[r*DIM+d] * Wk[d*128+j];
      m[idx] = s;
    } else if (idx < N_RELC*128 + N_RELC){
      int r = idx - N_RELC*128;
      float s = 0.f;
      for (int d = 0; d < DIM; ++d) s += Wkb[d] * rel[r*DIM+d];
      b[r] = s;
    }
  } else if (bid < FR_R2){
    // wat[k*64+d] = Wa[d*64+k] (2 blocks x 2048 entries)
    int base = (bid - FR_TR)*2048;
    for (int i = t; i < 2048; i += 256){
      int idx = base + i;
      int k = idx >> 6, d = idx & 63;
      wat[idx] = Wa[d*64 + k];
      wbt[idx] = Wb[d*64 + k];
    }
  } else if (bid < FR_KG){
    int i = (bid - FR_R2)*256 + t;
    if (i < 1024) r2_user[user_ids[i] - N_ENT] = 1;
    else if (i < 3072) r2_item[item_ids[i - 1024]] = 1;
  } else if (bid < FR_MK){
    int e = (bid - FR_KG)*256 + t;
    if (e <= NEDGE){
      int hc = (e < NEDGE) ? h_list[e] : N_ENT;
      int hp = (e == 0) ? -1 : h_list[e-1];
      for (int s = hp+1; s <= hc; ++s) off[s] = e;
    }
  } else {
    // mark: LDS bitmaps of r2 sets built from ids (no dependency on r2 scatter)
    __shared__ u32 bm_item[(N_ENT + 31)/32];   // 12.5 KB
    __shared__ u32 bm_user[(N_USR + 31)/32];   // 3.75 KB
    for (int i = t; i < (N_ENT+31)/32; i += 256) bm_item[i] = 0;
    for (int i = t; i < (N_USR+31)/32; i += 256) bm_user[i] = 0;
    __syncthreads();
    for (int i = t; i < 3072; i += 256){
      if (i < 1024){ int u = user_ids[i] - N_ENT; atomicOr(&bm_user[u>>5], 1u << (u&31)); }
      else { int it = item_ids[i - 1024]; atomicOr(&bm_item[it>>5], 1u << (it&31)); }
    }
    __syncthreads();
    int i = (bid - FR_MK)*256 + t;
    if (i < INTER/4){
      int4 ar = a_row4[i];
      int4 ac = a_col4[i];
      #pragma unroll
      for (int k = 0; k < 4; ++k){
        int it = (&ar.x)[k];
        int uu = (&ac.x)[k] - N_ENT;
        if ((bm_item[it>>5] >> (it&31)) & 1u) need_u[uu] = 1;
        if ((bm_user[uu>>5] >> (uu&31)) & 1u) need_d[it] = 1;
      }
    }
  }
}

// fused: list compaction (blocks < CPT_NB) + fixed-stride CSR fill (4 pairs/thread)
// Gated item rows (need_d) are EXCLUDED from list_s1 — their collab row is
// computed inside k_l1g's att branch (per-row gate fusion).
__global__ void __launch_bounds__(256) k_buildfill(
    const int* __restrict__ a_row, const int* __restrict__ a_col,
    const float* __restrict__ a_vals,
    const u8* __restrict__ need_d, const u8* __restrict__ need_u,
    const u8* __restrict__ r2_item, const u8* __restrict__ r2_user,
    int* __restrict__ list_gate, int* __restrict__ list_s1,
    int* __restrict__ counters, int* __restrict__ cnt, int2* __restrict__ csr){
  if (blockIdx.x < CPT_NB){
    __shared__ u64 mg_sh[16], ms_sh[16];
    __shared__ int pre_g[16], pre_s[16];
    __shared__ int base_sh[2];
    int t = threadIdx.x;
    int wave = t >> 6, lane = t & 63;
    bool pg[4], ps[4];
    int ibase = blockIdx.x*1024;
    #pragma unroll
    for (int k = 0; k < 4; ++k){
      int i = ibase + k*256 + t;
      bool g = false, s = false;
      if (i < N_TOTN){
        if (i < N_ENT){ g = need_d[i] != 0; s = (!g) && (r2_item[i] != 0); }
        else { int u = i - N_ENT; s = (need_u[u] != 0) || (r2_user[u] != 0); }
      }
      pg[k] = g; ps[k] = s;
      u64 mg = __ballot(g), ms = __ballot(s);
      if (lane == 0){ mg_sh[k*4 + wave] = mg; ms_sh[k*4 + wave] = ms; }
    }
    __syncthreads();
    if (t == 0){
      int sg = 0, ss = 0;
      for (int j = 0; j < 16; ++j){
        pre_g[j] = sg; sg += __popcll(mg_sh[j]);
        pre_s[j] = ss; ss += __popcll(ms_sh[j]);
      }
      base_sh[0] = sg ? atomicAdd(&counters[0], sg) : 0;
      base_sh[1] = ss ? atomicAdd(&counters[1], ss) : 0;
    }
    __syncthreads();
    int bg = base_sh[0], bs = base_sh[1];
    u64 lmask = (1ull << lane) - 1;
    #pragma unroll
    for (int k = 0; k < 4; ++k){
      int i = ibase + k*256 + t;
      if (pg[k]) list_gate[bg + pre_g[k*4+wave] + __popcll(mg_sh[k*4+wave] & lmask)] = i;
      if (ps[k]) list_s1 [bs + pre_s[k*4+wave] + __popcll(ms_sh[k*4+wave] & lmask)] = i;
    }
  } else {
    int i = (blockIdx.x - CPT_NB)*256 + threadIdx.x;
    if (i >= INTER/4) return;
    int4 ar = ((const int4*)a_row)[i];
    int4 ac = ((const int4*)a_col)[i];
    float4 av0 = ((const float4*)a_vals)[i];
    float4 av1 = ((const float4*)(a_vals + INTER))[i];
    #pragma unroll
    for (int k = 0; k < 4; ++k){
      int it = (&ar.x)[k];
      int uc = (&ac.x)[k];
      int uu = uc - N_ENT;
      if (need_d[it] | r2_item[it]){
        int p = atomicAdd(&cnt[it], 1);
        if (p < RSTR) csr[((size_t)it << 6) + p] = make_int2(uc, __float_as_int((&av0.x)[k]));
      }
      if (need_u[uu] | r2_user[uu]){
        int p = atomicAdd(&cnt[uc], 1);
        if (p < RSTR) csr[((size_t)uc << 6) + p] = make_int2(it, __float_as_int((&av1.x)[k]));
      }
    }
  }
}

// fused layer-1 + per-row gate. R8: DYNAMIC WAVE-BATCHED ROW POOL.
// R7's static 1024/1024 att/sp block split had ~2-3x per-row work skew ->
// sp blocks drained early, time-avg occupancy 42%. Now one combined row
// space [0,n0)=gated, [n0,ntot)=s1; each wave atomically grabs 4 rows
// (one per 16-lane group; ~7K wave-fetches, negligible contention).
// Quads are type-homogeneous except at the n0 seam. All waves stay busy
// until the pool drains. LDS-free; lb(256,8) -> 32 waves/CU.
__global__ void __launch_bounds__(256, 8) k_l1g(const float4* __restrict__ ent4,
    const float4* __restrict__ m4, const float* __restrict__ bvec,
    const float4* __restrict__ wat4, const float4* __restrict__ wbt4,
    const int* __restrict__ off, const int* __restrict__ t_list,
    const int* __restrict__ r_list, const int* __restrict__ list_gate,
    const int* __restrict__ list_s1, int* __restrict__ counters,
    const int* __restrict__ cnt, const int2* __restrict__ csr,
    float4* __restrict__ collab4, float4* __restrict__ x2_4){
  int t = threadIdx.x;
  int sub = t & 15;
  int gig = (t >> 4) & 3;            // group index within wave
  int n0 = counters[0];
  int ntot = n0 + counters[1];
  for (;;){
    int base;
    if ((t & 63) == 0) base = atomicAdd(&counters[16], 4);
    base = __shfl(base, (t & 192), 64);   // broadcast from wave's lane 0
    if (base >= ntot) break;
    int idx = base + gig;
    if (idx >= ntot) continue;       // partial last quad (wave stays in loop)
    if (idx < n0){
      int s = list_gate[idx];
      // --- attention -> kg (in-register) ---
      int beg = off[s], end = off[s+1];
      float4 h4 = ent4[(size_t)s*16 + sub];
      float l = 0.f;
      float4 acc = {0.f,0.f,0.f,0.f};
      for (int bb = beg; bb < end; bb += 16){
        int mch = end - bb; if (mch > 16) mch = 16;
        int tj = 0, rj = 0;
        if (sub < mch){ tj = t_list[bb + sub]; rj = r_list[bb + sub]; }
        #pragma unroll 4
        for (int j = 0; j < mch; ++j){
          int ti = __shfl(tj, j, 16);
          int r  = __shfl(rj, j, 16);
          float4 t4 = ent4[(size_t)ti*16 + sub];
          float4 mt = m4[r*32 + sub];        // m_rel: 16KB, L1-resident
          float4 mh = m4[r*32 + 16 + sub];
          float v = t4.x*mt.x + t4.y*mt.y + t4.z*mt.z + t4.w*mt.w
                  + h4.x*mh.x + h4.y*mh.y + h4.z*mh.z + h4.w*mh.w;
          v = grp_sum16(v) + bvec[r];
          v = (v >= 0.f) ? v : SLOPE * v;
          float w = __expf(v);
          l += w;
          acc.x += w*t4.x; acc.y += w*t4.y; acc.z += w*t4.z; acc.w += w*t4.w;
        }
      }
      float inv = (end > beg) ? 1.f / l : 0.f;
      float4 kg = {acc.x*inv, acc.y*inv, acc.z*inv, acc.w*inv};
      // --- this row's collab (CSR spmm, deg ~5 for items) ---
      int deg = cnt[s]; if (deg > RSTR) deg = RSTR;
      size_t base0 = (size_t)s << 6;
      float4 cb = {0.f,0.f,0.f,0.f};
      for (int b = 0; b < deg; b += 16){
        int mch = deg - b; if (mch > 16) mch = 16;
        int2 e = make_int2(0, 0);
        if (sub < mch) e = csr[base0 + b + sub];
        #pragma unroll 4
        for (int j = 0; j < mch; ++j){
          int cj = __shfl(e.x, j, 16);
          float vj = __int_as_float(__shfl(e.y, j, 16));
          float4 sv = ent4[(size_t)cj*16 + sub];
          cb.x += vj*sv.x; cb.y += vj*sv.y; cb.z += vj*sv.z; cb.w += vj*sv.w;
        }
      }
      // --- gate: ga[d] = sum_k kg[k]*Wa[d][k] + cb[k]*Wb[d][k] ---
      // wat4[k*16+sub] = WaT[k][4sub..4sub+3]; coalesced L1-hit loads.
      float4 ga = {0.f,0.f,0.f,0.f};
      for (int kk = 0; kk < 16; ++kk){
        float kqx = __shfl(kg.x, kk, 16), kqy = __shfl(kg.y, kk, 16);
        float kqz = __shfl(kg.z, kk, 16), kqw = __shfl(kg.w, kk, 16);
        float cqx = __shfl(cb.x, kk, 16), cqy = __shfl(cb.y, kk, 16);
        float cqz = __shfl(cb.z, kk, 16), cqw = __shfl(cb.w, kk, 16);
        int k0 = kk*4;
        float4 wa0 = wat4[(k0+0)*16 + sub];
        float4 wa1 = wat4[(k0+1)*16 + sub];
        float4 wa2 = wat4[(k0+2)*16 + sub];
        float4 wa3 = wat4[(k0+3)*16 + sub];
        float4 wb0 = wbt4[(k0+0)*16 + sub];
        float4 wb1 = wbt4[(k0+1)*16 + sub];
        float4 wb2 = wbt4[(k0+2)*16 + sub];
        float4 wb3 = wbt4[(k0+3)*16 + sub];
        ga.x += kqx*wa0.x + kqy*wa1.x + kqz*wa2.x + kqw*wa3.x
              + cqx*wb0.x + cqy*wb1.x + cqz*wb2.x + cqw*wb3.x;
        ga.y += kqx*wa0.y + kqy*wa1.y + kqz*wa2.y + kqw*wa3.y
              + cqx*wb0.y + cqy*wb1.y + cqz*wb2.y + cqw*wb3.y;
        ga.z += kqx*wa0.z + kqy*wa1.z + kqz*wa2.z + kqw*wa3.z
              + cqx*wb0.z + cqy*wb1.z + cqz*wb2.z + cqw*wb3.z;
        ga.w += kqx*wa0.w + kqy*wa1.w + kqz*wa2.w + kqw*wa3.w
              + cqx*wb0.w + cqy*wb1.w + cqz*wb2.w + cqw*wb3.w;
      }
      float4 o;
      #pragma unroll
      for (int j = 0; j < 4; ++j){
        float g = 1.f / (1.f + __expf(-(&ga.x)[j]));
        (&o.x)[j] = g*(&kg.x)[j] + (1.f - g)*(&cb.x)[j];
      }
      collab4[(size_t)s*16 + sub] = cb;
      x2_4[(size_t)s*16 + sub] = o;
    } else {
      int i = list_s1[idx - n0];
      int deg = cnt[i]; if (deg > RSTR) deg = RSTR;
      size_t base0 = (size_t)i << 6;
      float4 acc = {0.f,0.f,0.f,0.f};
      for (int b = 0; b < deg; b += 16){
        int mch = deg - b; if (mch > 16) mch = 16;
        int2 e = make_int2(0, 0);
        if (sub < mch) e = csr[base0 + b + sub];
        #pragma unroll 8
        for (int j = 0; j < mch; ++j){
          int cj = __shfl(e.x, j, 16);
          float vj = __int_as_float(__shfl(e.y, j, 16));
          float4 sv = ent4[(size_t)cj*16 + sub];   // src = all_embed table
          acc.x += vj*sv.x; acc.y += vj*sv.y; acc.z += vj*sv.z; acc.w += vj*sv.w;
        }
      }
      if (i < N_ENT) collab4[(size_t)i*16 + sub] = acc;
      else x2_4[(size_t)i*16 + sub] = acc;
    }
  }
}

// fused spmm-2 + gather: one 64-lane wave per output row, lane = dim.
__global__ void __launch_bounds__(256) k_spmm2g(const int* __restrict__ cnt,
    const int2* __restrict__ csr, const float* __restrict__ x2,
    const float* __restrict__ all_embed, const float* __restrict__ collab1,
    const int* __restrict__ user_ids, const int* __restrict__ item_ids,
    float* __restrict__ user_e, float* __restrict__ item_e){
  int lane = threadIdx.x & 63;
  int g = (blockIdx.x*256 + threadIdx.x) >> 6;
  if (g >= 3072) return;
  int id;
  float b1;
  if (g < 1024){
    id = user_ids[g];                            // >= N_ENT
    b1 = x2[(size_t)id*64 + lane];               // users1 lives in x2
  } else {
    id = item_ids[g - 1024];
    b1 = collab1[(size_t)id*64 + lane];
  }
  float acc = all_embed[(size_t)id*64 + lane] + b1;
  int deg = cnt[id]; if (deg > RSTR) deg = RSTR;
  size_t base0 = (size_t)id << 6;
  int2 e = make_int2(0, 0);
  if (lane < deg) e = csr[base0 + lane];
  #pragma unroll 8
  for (int j = 0; j < deg; ++j){
    int cj = __shfl(e.x, j, 64);
    float vj = __int_as_float(__shfl(e.y, j, 64));
    acc += vj * x2[(size_t)cj*64 + lane];
  }
  if (g < 1024) user_e[(size_t)g*64 + lane] = acc;
  else item_e[(size_t)(g - 1024)*64 + lane] = acc;
}

// out[1024][2048] = user_e @ item_e^T, 64x64 tiles, 4x4 micro-tile, K=64
__global__ void __launch_bounds__(256) k_out(const float* __restrict__ ue,
    const float* __restrict__ ie, float* __restrict__ out){
  __shared__ float ash[64][65];
  __shared__ float bsh[64][65];
  int row0 = blockIdx.y * 64, col0 = blockIdx.x * 64;
  for (int i = threadIdx.x; i < 64*64; i += 256){
    int r = i >> 6, c = i & 63;
    ash[r][c] = ue[(size_t)(row0 + r)*DIM + c];
    bsh[r][c] = ie[(size_t)(col0 + r)*DIM + c];
  }
  __syncthreads();
  int tx = threadIdx.x & 15, ty = threadIdx.x >> 4;
  int r0 = ty*4, c0 = tx*4;
  float acc[4][4] = {};
  #pragma unroll
  for (int k = 0; k < 64; ++k){
    float a0 = ash[r0][k], a1 = ash[r0+1][k], a2 = ash[r0+2][k], a3 = ash[r0+3][k];
    float b0 = bsh[c0][k], b1 = bsh[c0+1][k], b2 = bsh[c0+2][k], b3 = bsh[c0+3][k];
    acc[0][0] += a0*b0; acc[0][1] += a0*b1; acc[0][2] += a0*b2; acc[0][3] += a0*b3;
    acc[1][0] += a1*b0; acc[1][1] += a1*b1; acc[1][2] += a1*b2; acc[1][3] += a1*b3;
    acc[2][0] += a2*b0; acc[2][1] += a2*b1; acc[2][2] += a2*b2; acc[2][3] += a2*b3;
    acc[3][0] += a3*b0; acc[3][1] += a3*b1; acc[3][2] += a3*b2; acc[3][3] += a3*b3;
  }
  #pragma unroll
  for (int i = 0; i < 4; ++i){
    float4 o = {acc[i][0], acc[i][1], acc[i][2], acc[i][3]};
    *(float4*)&out[(size_t)(row0 + r0 + i)*2048 + col0 + c0] = o;
  }
}

extern "C" void kernel_launch(void* const* d_in, const int* in_sizes, int n_in,
                              void* d_out, int out_size, void* d_ws, size_t ws_size,
                              hipStream_t stream){
  const float* all_embed = (const float*)d_in[0];
  const float* rel_embed = (const float*)d_in[1];
  const float* Wk_w      = (const float*)d_in[2];
  const float* Wk_b      = (const float*)d_in[3];
  const float* Wa_w      = (const float*)d_in[4];
  const float* Wb_w      = (const float*)d_in[5];
  const float* a_vals    = (const float*)d_in[6];
  const int* user_ids   = (const int*)d_in[7];
  const int* item_ids   = (const int*)d_in[8];
  const int* h_list     = (const int*)d_in[9];
  const int* t_list     = (const int*)d_in[10];
  const int* r_list     = (const int*)d_in[11];
  const int* a_row      = (const int*)d_in[12];
  const int* a_col      = (const int*)d_in[13];
  float* out = (float*)d_out;

  char* p = (char*)d_ws;
  auto alloc = [&](size_t bytes)->void*{
    void* r = (void*)p;
    p += (bytes + 255) & ~(size_t)255;
    return r;
  };
  float* m_rel   = (float*)alloc((size_t)N_RELC*128*4);
  float* b_rel   = (float*)alloc((size_t)N_RELC*4);
  float* wat     = (float*)alloc((size_t)64*64*4);
  float* wbt     = (float*)alloc((size_t)64*64*4);
  int*   kg_off  = (int*)  alloc((size_t)(N_ENT+1)*4);
  // zero region (separate memset BEFORE k_front — do not fuse, see R11 race)
  size_t zbytes = (size_t)N_TOTN*4 + 256 + (2*(size_t)N_ENT + 2*(size_t)N_USR);
  char*  zbase  = (char*)alloc(zbytes);
  int*   cnt      = (int*)zbase;
  int*   counters = (int*)(zbase + (size_t)N_TOTN*4);   // [0]=gate n, [1]=s1 n, [16]=row cursor
  u8*    r2_item  = (u8*)(zbase + (size_t)N_TOTN*4 + 256);
  u8*    r2_user  = r2_item + N_ENT;
  u8*    need_d   = r2_user + N_USR;
  u8*    need_u   = need_d + N_ENT;
  int2*  csr     = (int2*) alloc((size_t)N_TOTN*RSTR*8);
  int*   list_gate = (int*)alloc((size_t)N_ENT*4);
  int*   list_s1   = (int*)alloc((size_t)N_TOTN*4);
  float* collab1 = (float*)alloc((size_t)N_ENT*DIM*4);
  float* x2      = (float*)alloc((size_t)N_TOTN*DIM*4);  // [dual ; users1]
  float* user_e  = (float*)alloc((size_t)1024*DIM*4);
  float* item_e  = (float*)alloc((size_t)2048*DIM*4);

  hipMemsetAsync(zbase, 0, zbytes, stream);
  k_front<<<FR_NB, 256, 0, stream>>>(rel_embed, Wk_w, Wk_b, m_rel, b_rel,
      Wa_w, Wb_w, wat, wbt, user_ids, item_ids, r2_item, r2_user,
      h_list, kg_off, (const int4*)a_row, (const int4*)a_col, need_d, need_u);
  k_buildfill<<<CPT_NB + FILL_NB, 256, 0, stream>>>(a_row, a_col, a_vals,
      need_d, need_u, r2_item, r2_user, list_gate, list_s1, counters, cnt, csr);
  // after k_buildfill: cnt[r] == deg(r) for needed rows, csr row r at [r*64, r*64+deg)

  k_l1g<<<L1G_NB, 256, 0, stream>>>((const float4*)all_embed,
      (const float4*)m_rel, b_rel, (const float4*)wat, (const float4*)wbt,
      kg_off, t_list, r_list, list_gate, list_s1, counters, cnt, csr,
      (float4*)collab1, (float4*)x2);

  k_spmm2g<<<768, 256, 0, stream>>>(cnt, csr, x2, all_embed, collab1,
      user_ids, item_ids, user_e, item_e);
  dim3 grid_out(2048/64, 1024/64);
  k_out<<<grid_out, 256, 0, stream>>>(user_e, item_e, out);
}

// Round 9
// 207.234 us; speedup vs baseline: 1.6082x; 1.6082x over previous
//
#include <hip/hip_runtime.h>

#define N_ENT 100000
#define N_USR 30000
#define N_TOTN 130000
#define N_RELC 32
#define DIM 64
#define NEDGE 500000
#define INTER 500000
#define SLOPE 0.01f
#define CPT_NB 127     // compaction blocks: 127*1024 = 130048 >= 130000
#define FILL_NB 489    // ceil(125000/256) — 4 pairs per thread
#define RSTR 64        // fixed CSR row stride (max degree; Poisson(16.7) tail ~1e-16)
#define L1G_NB 2048    // 8 blocks/CU, LDS-free, 32 waves/CU
// k_front block layout: [0,17) m_rel | [17,19) W transpose | [19,31) r2 scatter
//                       [31,1985) kg_off | [1985,2474) mark(LDS-bitmap)
#define FR_TR 17
#define FR_R2 19
#define FR_KG 31
#define FR_MK 1985
#define FR_NB 2474

typedef unsigned char u8;
typedef unsigned int u32;
typedef unsigned long long u64;

__device__ __forceinline__ float grp_sum16(float v){
  v += __shfl_xor(v, 8, 64);
  v += __shfl_xor(v, 4, 64);
  v += __shfl_xor(v, 2, 64);
  v += __shfl_xor(v, 1, 64);
  return v;
}
// sum across the wave's 4 sub-groups (lanes xor 16, 32)
__device__ __forceinline__ float xg_sum(float v){
  v += __shfl_xor(v, 16, 64);
  v += __shfl_xor(v, 32, 64);
  return v;
}
__device__ __forceinline__ void xg_sum4(float4& v){
  v.x = xg_sum(v.x); v.y = xg_sum(v.y); v.z = xg_sum(v.z); v.w = xg_sum(v.w);
}

// fused front: m_rel/b_rel + Wa/Wb transpose + r2 scatter + kg_off scan +
// mark (mark blocks rebuild r2 as LDS bitmaps from the 3K ids directly).
// NOTE: zero-init stays a SEPARATE prior hipMemsetAsync (R11 race).
// NOTE 2: manual grid barriers / cooperative launch are CONDEMNED on this
// stack (R1 silent no-launch; R2/R3 HSA aborts). Regular launches only.
// NOTE 3: dispatch-boundary gap measured ~3us (R6->R7) — merging kernels is
// only worth it if it also removes work or improves balance.
// NOTE 4: same-address global atomic work-stealing is CONDEMNED (R8: 16K
// single-address RMWs serialized ~150us; occupancy 66% but VALUBusy 3.9%).
__global__ void __launch_bounds__(256) k_front(
    const float* __restrict__ rel, const float* __restrict__ Wk,
    const float* __restrict__ Wkb, float* __restrict__ m, float* __restrict__ b,
    const float* __restrict__ Wa, const float* __restrict__ Wb,
    float* __restrict__ wat, float* __restrict__ wbt,
    const int* __restrict__ user_ids, const int* __restrict__ item_ids,
    u8* __restrict__ r2_item, u8* __restrict__ r2_user,
    const int* __restrict__ h_list, int* __restrict__ off,
    const int4* __restrict__ a_row4, const int4* __restrict__ a_col4,
    u8* __restrict__ need_d, u8* __restrict__ need_u){
  int bid = blockIdx.x;
  int t = threadIdx.x;
  if (bid < FR_TR){
    int idx = bid*256 + t;
    if (idx < N_RELC*128){
      int r = idx >> 7, j = idx & 127;
      float s = 0.f;
      for (int d = 0; d < DIM; ++d) s += rel[r*DIM+d] * Wk[d*128+j];
      m[idx] = s;
    } else if (idx < N_RELC*128 + N_RELC){
      int r = idx - N_RELC*128;
      float s = 0.f;
      for (int d = 0; d < DIM; ++d) s += Wkb[d] * rel[r*DIM+d];
      b[r] = s;
    }
  } else if (bid < FR_R2){
    // wat[k*64+d] = Wa[d*64+k] (2 blocks x 2048 entries)
    int base = (bid - FR_TR)*2048;
    for (int i = t; i < 2048; i += 256){
      int idx = base + i;
      int k = idx >> 6, d = idx & 63;
      wat[idx] = Wa[d*64 + k];
      wbt[idx] = Wb[d*64 + k];
    }
  } else if (bid < FR_KG){
    int i = (bid - FR_R2)*256 + t;
    if (i < 1024) r2_user[user_ids[i] - N_ENT] = 1;
    else if (i < 3072) r2_item[item_ids[i - 1024]] = 1;
  } else if (bid < FR_MK){
    int e = (bid - FR_KG)*256 + t;
    if (e <= NEDGE){
      int hc = (e < NEDGE) ? h_list[e] : N_ENT;
      int hp = (e == 0) ? -1 : h_list[e-1];
      for (int s = hp+1; s <= hc; ++s) off[s] = e;
    }
  } else {
    // mark: LDS bitmaps of r2 sets built from ids (no dependency on r2 scatter)
    __shared__ u32 bm_item[(N_ENT + 31)/32];   // 12.5 KB
    __shared__ u32 bm_user[(N_USR + 31)/32];   // 3.75 KB
    for (int i = t; i < (N_ENT+31)/32; i += 256) bm_item[i] = 0;
    for (int i = t; i < (N_USR+31)/32; i += 256) bm_user[i] = 0;
    __syncthreads();
    for (int i = t; i < 3072; i += 256){
      if (i < 1024){ int u = user_ids[i] - N_ENT; atomicOr(&bm_user[u>>5], 1u << (u&31)); }
      else { int it = item_ids[i - 1024]; atomicOr(&bm_item[it>>5], 1u << (it&31)); }
    }
    __syncthreads();
    int i = (bid - FR_MK)*256 + t;
    if (i < INTER/4){
      int4 ar = a_row4[i];
      int4 ac = a_col4[i];
      #pragma unroll
      for (int k = 0; k < 4; ++k){
        int it = (&ar.x)[k];
        int uu = (&ac.x)[k] - N_ENT;
        if ((bm_item[it>>5] >> (it&31)) & 1u) need_u[uu] = 1;
        if ((bm_user[uu>>5] >> (uu&31)) & 1u) need_d[it] = 1;
      }
    }
  }
}

// fused: list compaction (blocks < CPT_NB) + fixed-stride CSR fill (4 pairs/thread)
// Gated item rows (need_d) are EXCLUDED from list_s1 — their collab row is
// computed inside k_l1g's att branch (per-row gate fusion).
__global__ void __launch_bounds__(256) k_buildfill(
    const int* __restrict__ a_row, const int* __restrict__ a_col,
    const float* __restrict__ a_vals,
    const u8* __restrict__ need_d, const u8* __restrict__ need_u,
    const u8* __restrict__ r2_item, const u8* __restrict__ r2_user,
    int* __restrict__ list_gate, int* __restrict__ list_s1,
    int* __restrict__ counters, int* __restrict__ cnt, int2* __restrict__ csr){
  if (blockIdx.x < CPT_NB){
    __shared__ u64 mg_sh[16], ms_sh[16];
    __shared__ int pre_g[16], pre_s[16];
    __shared__ int base_sh[2];
    int t = threadIdx.x;
    int wave = t >> 6, lane = t & 63;
    bool pg[4], ps[4];
    int ibase = blockIdx.x*1024;
    #pragma unroll
    for (int k = 0; k < 4; ++k){
      int i = ibase + k*256 + t;
      bool g = false, s = false;
      if (i < N_TOTN){
        if (i < N_ENT){ g = need_d[i] != 0; s = (!g) && (r2_item[i] != 0); }
        else { int u = i - N_ENT; s = (need_u[u] != 0) || (r2_user[u] != 0); }
      }
      pg[k] = g; ps[k] = s;
      u64 mg = __ballot(g), ms = __ballot(s);
      if (lane == 0){ mg_sh[k*4 + wave] = mg; ms_sh[k*4 + wave] = ms; }
    }
    __syncthreads();
    if (t == 0){
      int sg = 0, ss = 0;
      for (int j = 0; j < 16; ++j){
        pre_g[j] = sg; sg += __popcll(mg_sh[j]);
        pre_s[j] = ss; ss += __popcll(ms_sh[j]);
      }
      base_sh[0] = sg ? atomicAdd(&counters[0], sg) : 0;
      base_sh[1] = ss ? atomicAdd(&counters[1], ss) : 0;
    }
    __syncthreads();
    int bg = base_sh[0], bs = base_sh[1];
    u64 lmask = (1ull << lane) - 1;
    #pragma unroll
    for (int k = 0; k < 4; ++k){
      int i = ibase + k*256 + t;
      if (pg[k]) list_gate[bg + pre_g[k*4+wave] + __popcll(mg_sh[k*4+wave] & lmask)] = i;
      if (ps[k]) list_s1 [bs + pre_s[k*4+wave] + __popcll(ms_sh[k*4+wave] & lmask)] = i;
    }
  } else {
    int i = (blockIdx.x - CPT_NB)*256 + threadIdx.x;
    if (i >= INTER/4) return;
    int4 ar = ((const int4*)a_row)[i];
    int4 ac = ((const int4*)a_col)[i];
    float4 av0 = ((const float4*)a_vals)[i];
    float4 av1 = ((const float4*)(a_vals + INTER))[i];
    #pragma unroll
    for (int k = 0; k < 4; ++k){
      int it = (&ar.x)[k];
      int uc = (&ac.x)[k];
      int uu = uc - N_ENT;
      if (need_d[it] | r2_item[it]){
        int p = atomicAdd(&cnt[it], 1);
        if (p < RSTR) csr[((size_t)it << 6) + p] = make_int2(uc, __float_as_int((&av0.x)[k]));
      }
      if (need_u[uu] | r2_user[uu]){
        int p = atomicAdd(&cnt[uc], 1);
        if (p < RSTR) csr[((size_t)uc << 6) + p] = make_int2(it, __float_as_int((&av1.x)[k]));
      }
    }
  }
}

// fused layer-1 + per-row gate. R9: WAVE-PER-ROW, static interleaved pool.
// R8's atomic fetch is reverted (condemned). One 64-lane wave owns one row;
// its 4 sub-groups process 4 edges concurrently (16 gathers in flight vs 4)
// and split the gate matvec 4 ways; cross-group shfl_xor(16/32) reduction.
// Combined row space [0,n0)=gated, [n0,ntot)=s1 strided by wave id -> each
// wave draws a MIX of heavy att rows and light sp rows (balance w/o atomics).
__global__ void __launch_bounds__(256, 8) k_l1g(const float4* __restrict__ ent4,
    const float4* __restrict__ m4, const float* __restrict__ bvec,
    const float4* __restrict__ wat4, const float4* __restrict__ wbt4,
    const int* __restrict__ off, const int* __restrict__ t_list,
    const int* __restrict__ r_list, const int* __restrict__ list_gate,
    const int* __restrict__ list_s1, const int* __restrict__ counters,
    const int* __restrict__ cnt, const int2* __restrict__ csr,
    float4* __restrict__ collab4, float4* __restrict__ x2_4){
  int t = threadIdx.x;
  int sub = t & 15;
  int gig = (t >> 4) & 3;            // sub-group index within wave
  int j0 = gig * 4;                  // this group's edge/k slice base
  int n0 = counters[0];
  int ntot = n0 + counters[1];
  int w = (blockIdx.x*256 + t) >> 6;
  const int nw = L1G_NB * 4;
  for (int idx = w; idx < ntot; idx += nw){
    if (idx < n0){
      int s = list_gate[idx];
      // --- attention -> kg; 4 edges in flight per wave-quad ---
      int beg = off[s], end = off[s+1];
      float4 h4 = ent4[(size_t)s*16 + sub];
      float l = 0.f;
      float4 acc = {0.f,0.f,0.f,0.f};
      for (int bb = beg; bb < end; bb += 16){
        int mch = end - bb; if (mch > 16) mch = 16;
        int tj = 0, rj = 0;
        if (sub < mch){ tj = t_list[bb + sub]; rj = r_list[bb + sub]; }
        #pragma unroll
        for (int jj = 0; jj < 4; ++jj){
          int j = j0 + jj;
          if (j < mch){
            int ti = __shfl(tj, j, 16);
            int r  = __shfl(rj, j, 16);
            float4 t4 = ent4[(size_t)ti*16 + sub];
            float4 mt = m4[r*32 + sub];        // m_rel: 16KB, L1-resident
            float4 mh = m4[r*32 + 16 + sub];
            float v = t4.x*mt.x + t4.y*mt.y + t4.z*mt.z + t4.w*mt.w
                    + h4.x*mh.x + h4.y*mh.y + h4.z*mh.z + h4.w*mh.w;
            v = grp_sum16(v) + bvec[r];
            v = (v >= 0.f) ? v : SLOPE * v;
            float wgt = __expf(v);
            l += wgt;
            acc.x += wgt*t4.x; acc.y += wgt*t4.y; acc.z += wgt*t4.z; acc.w += wgt*t4.w;
          }
        }
      }
      l = xg_sum(l);
      xg_sum4(acc);
      float inv = (end > beg) ? 1.f / l : 0.f;
      float4 kg = {acc.x*inv, acc.y*inv, acc.z*inv, acc.w*inv};
      // --- this row's collab (CSR spmm); 4 edges in flight ---
      int deg = cnt[s]; if (deg > RSTR) deg = RSTR;
      size_t base0 = (size_t)s << 6;
      float4 cb = {0.f,0.f,0.f,0.f};
      for (int b = 0; b < deg; b += 16){
        int mch = deg - b; if (mch > 16) mch = 16;
        int2 e = make_int2(0, 0);
        if (sub < mch) e = csr[base0 + b + sub];
        #pragma unroll
        for (int jj = 0; jj < 4; ++jj){
          int j = j0 + jj;
          if (j < mch){
            int cj = __shfl(e.x, j, 16);
            float vj = __int_as_float(__shfl(e.y, j, 16));
            float4 sv = ent4[(size_t)cj*16 + sub];
            cb.x += vj*sv.x; cb.y += vj*sv.y; cb.z += vj*sv.z; cb.w += vj*sv.w;
          }
        }
      }
      xg_sum4(cb);
      // --- gate: 16 k-steps split 4 ways across sub-groups ---
      float4 ga = {0.f,0.f,0.f,0.f};
      #pragma unroll
      for (int kkk = 0; kkk < 4; ++kkk){
        int kk = j0 + kkk;
        float kqx = __shfl(kg.x, kk, 16), kqy = __shfl(kg.y, kk, 16);
        float kqz = __shfl(kg.z, kk, 16), kqw = __shfl(kg.w, kk, 16);
        float cqx = __shfl(cb.x, kk, 16), cqy = __shfl(cb.y, kk, 16);
        float cqz = __shfl(cb.z, kk, 16), cqw = __shfl(cb.w, kk, 16);
        int k0 = kk*4;
        float4 wa0 = wat4[(k0+0)*16 + sub];
        float4 wa1 = wat4[(k0+1)*16 + sub];
        float4 wa2 = wat4[(k0+2)*16 + sub];
        float4 wa3 = wat4[(k0+3)*16 + sub];
        float4 wb0 = wbt4[(k0+0)*16 + sub];
        float4 wb1 = wbt4[(k0+1)*16 + sub];
        float4 wb2 = wbt4[(k0+2)*16 + sub];
        float4 wb3 = wbt4[(k0+3)*16 + sub];
        ga.x += kqx*wa0.x + kqy*wa1.x + kqz*wa2.x + kqw*wa3.x
              + cqx*wb0.x + cqy*wb1.x + cqz*wb2.x + cqw*wb3.x;
        ga.y += kqx*wa0.y + kqy*wa1.y + kqz*wa2.y + kqw*wa3.y
              + cqx*wb0.y + cqy*wb1.y + cqz*wb2.y + cqw*wb3.y;
        ga.z += kqx*wa0.z + kqy*wa1.z + kqz*wa2.z + kqw*wa3.z
              + cqx*wb0.z + cqy*wb1.z + cqz*wb2.z + cqw*wb3.z;
        ga.w += kqx*wa0.w + kqy*wa1.w + kqz*wa2.w + kqw*wa3.w
              + cqx*wb0.w + cqy*wb1.w + cqz*wb2.w + cqw*wb3.w;
      }
      xg_sum4(ga);
      float4 o;
      #pragma unroll
      for (int j = 0; j < 4; ++j){
        float g = 1.f / (1.f + __expf(-(&ga.x)[j]));
        (&o.x)[j] = g*(&kg.x)[j] + (1.f - g)*(&cb.x)[j];
      }
      if (gig == 0){
        collab4[(size_t)s*16 + sub] = cb;
        x2_4[(size_t)s*16 + sub] = o;
      }
    } else {
      int i = list_s1[idx - n0];
      int deg = cnt[i]; if (deg > RSTR) deg = RSTR;
      size_t base0 = (size_t)i << 6;
      float4 acc = {0.f,0.f,0.f,0.f};
      for (int b = 0; b < deg; b += 16){
        int mch = deg - b; if (mch > 16) mch = 16;
        int2 e = make_int2(0, 0);
        if (sub < mch) e = csr[base0 + b + sub];
        #pragma unroll
        for (int jj = 0; jj < 4; ++jj){
          int j = j0 + jj;
          if (j < mch){
            int cj = __shfl(e.x, j, 16);
            float vj = __int_as_float(__shfl(e.y, j, 16));
            float4 sv = ent4[(size_t)cj*16 + sub];   // src = all_embed table
            acc.x += vj*sv.x; acc.y += vj*sv.y; acc.z += vj*sv.z; acc.w += vj*sv.w;
          }
        }
      }
      xg_sum4(acc);
      if (gig == 0){
        if (i < N_ENT) collab4[(size_t)i*16 + sub] = acc;
        else x2_4[(size_t)i*16 + sub] = acc;
      }
    }
  }
}

// fused spmm-2 + gather: one 64-lane wave per output row, lane = dim.
__global__ void __launch_bounds__(256) k_spmm2g(const int* __restrict__ cnt,
    const int2* __restrict__ csr, const float* __restrict__ x2,
    const float* __restrict__ all_embed, const float* __restrict__ collab1,
    const int* __restrict__ user_ids, const int* __restrict__ item_ids,
    float* __restrict__ user_e, float* __restrict__ item_e){
  int lane = threadIdx.x & 63;
  int g = (blockIdx.x*256 + threadIdx.x) >> 6;
  if (g >= 3072) return;
  int id;
  float b1;
  if (g < 1024){
    id = user_ids[g];                            // >= N_ENT
    b1 = x2[(size_t)id*64 + lane];               // users1 lives in x2
  } else {
    id = item_ids[g - 1024];
    b1 = collab1[(size_t)id*64 + lane];
  }
  float acc = all_embed[(size_t)id*64 + lane] + b1;
  int deg = cnt[id]; if (deg > RSTR) deg = RSTR;
  size_t base0 = (size_t)id << 6;
  int2 e = make_int2(0, 0);
  if (lane < deg) e = csr[base0 + lane];
  #pragma unroll 8
  for (int j = 0; j < deg; ++j){
    int cj = __shfl(e.x, j, 64);
    float vj = __int_as_float(__shfl(e.y, j, 64));
    acc += vj * x2[(size_t)cj*64 + lane];
  }
  if (g < 1024) user_e[(size_t)g*64 + lane] = acc;
  else item_e[(size_t)(g - 1024)*64 + lane] = acc;
}

// out[1024][2048] = user_e @ item_e^T, 64x64 tiles, 4x4 micro-tile, K=64
__global__ void __launch_bounds__(256) k_out(const float* __restrict__ ue,
    const float* __restrict__ ie, float* __restrict__ out){
  __shared__ float ash[64][65];
  __shared__ float bsh[64][65];
  int row0 = blockIdx.y * 64, col0 = blockIdx.x * 64;
  for (int i = threadIdx.x; i < 64*64; i += 256){
    int r = i >> 6, c = i & 63;
    ash[r][c] = ue[(size_t)(row0 + r)*DIM + c];
    bsh[r][c] = ie[(size_t)(col0 + r)*DIM + c];
  }
  __syncthreads();
  int tx = threadIdx.x & 15, ty = threadIdx.x >> 4;
  int r0 = ty*4, c0 = tx*4;
  float acc[4][4] = {};
  #pragma unroll
  for (int k = 0; k < 64; ++k){
    float a0 = ash[r0][k], a1 = ash[r0+1][k], a2 = ash[r0+2][k], a3 = ash[r0+3][k];
    float b0 = bsh[c0][k], b1 = bsh[c0+1][k], b2 = bsh[c0+2][k], b3 = bsh[c0+3][k];
    acc[0][0] += a0*b0; acc[0][1] += a0*b1; acc[0][2] += a0*b2; acc[0][3] += a0*b3;
    acc[1][0] += a1*b0; acc[1][1] += a1*b1; acc[1][2] += a1*b2; acc[1][3] += a1*b3;
    acc[2][0] += a2*b0; acc[2][1] += a2*b1; acc[2][2] += a2*b2; acc[2][3] += a2*b3;
    acc[3][0] += a3*b0; acc[3][1] += a3*b1; acc[3][2] += a3*b2; acc[3][3] += a3*b3;
  }
  #pragma unroll
  for (int i = 0; i < 4; ++i){
    float4 o = {acc[i][0], acc[i][1], acc[i][2], acc[i][3]};
    *(float4*)&out[(size_t)(row0 + r0 + i)*2048 + col0 + c0] = o;
  }
}

extern "C" void kernel_launch(void* const* d_in, const int* in_sizes, int n_in,
                              void* d_out, int out_size, void* d_ws, size_t ws_size,
                              hipStream_t stream){
  const float* all_embed = (const float*)d_in[0];
  const float* rel_embed = (const float*)d_in[1];
  const float* Wk_w      = (const float*)d_in[2];
  const float* Wk_b      = (const float*)d_in[3];
  const float* Wa_w      = (const float*)d_in[4];
  const float* Wb_w      = (const float*)d_in[5];
  const float* a_vals    = (const float*)d_in[6];
  const int* user_ids   = (const int*)d_in[7];
  const int* item_ids   = (const int*)d_in[8];
  const int* h_list     = (const int*)d_in[9];
  const int* t_list     = (const int*)d_in[10];
  const int* r_list     = (const int*)d_in[11];
  const int* a_row      = (const int*)d_in[12];
  const int* a_col      = (const int*)d_in[13];
  float* out = (float*)d_out;

  char* p = (char*)d_ws;
  auto alloc = [&](size_t bytes)->void*{
    void* r = (void*)p;
    p += (bytes + 255) & ~(size_t)255;
    return r;
  };
  float* m_rel   = (float*)alloc((size_t)N_RELC*128*4);
  float* b_rel   = (float*)alloc((size_t)N_RELC*4);
  float* wat     = (float*)alloc((size_t)64*64*4);
  float* wbt     = (float*)alloc((size_t)64*64*4);
  int*   kg_off  = (int*)  alloc((size_t)(N_ENT+1)*4);
  // zero region (separate memset BEFORE k_front — do not fuse, see R11 race)
  size_t zbytes = (size_t)N_TOTN*4 + 256 + (2*(size_t)N_ENT + 2*(size_t)N_USR);
  char*  zbase  = (char*)alloc(zbytes);
  int*   cnt      = (int*)zbase;
  int*   counters = (int*)(zbase + (size_t)N_TOTN*4);   // [0]=gate n, [1]=s1 n
  u8*    r2_item  = (u8*)(zbase + (size_t)N_TOTN*4 + 256);
  u8*    r2_user  = r2_item + N_ENT;
  u8*    need_d   = r2_user + N_USR;
  u8*    need_u   = need_d + N_ENT;
  int2*  csr     = (int2*) alloc((size_t)N_TOTN*RSTR*8);
  int*   list_gate = (int*)alloc((size_t)N_ENT*4);
  int*   list_s1   = (int*)alloc((size_t)N_TOTN*4);
  float* collab1 = (float*)alloc((size_t)N_ENT*DIM*4);
  float* x2      = (float*)alloc((size_t)N_TOTN*DIM*4);  // [dual ; users1]
  float* user_e  = (float*)alloc((size_t)1024*DIM*4);
  float* item_e  = (float*)alloc((size_t)2048*DIM*4);

  hipMemsetAsync(zbase, 0, zbytes, stream);
  k_front<<<FR_NB, 256, 0, stream>>>(rel_embed, Wk_w, Wk_b, m_rel, b_rel,
      Wa_w, Wb_w, wat, wbt, user_ids, item_ids, r2_item, r2_user,
      h_list, kg_off, (const int4*)a_row, (const int4*)a_col, need_d, need_u);
  k_buildfill<<<CPT_NB + FILL_NB, 256, 0, stream>>>(a_row, a_col, a_vals,
      need_d, need_u, r2_item, r2_user, list_gate, list_s1, counters, cnt, csr);
  // after k_buildfill: cnt[r] == deg(r) for needed rows, csr row r at [r*64, r*64+deg)

  k_l1g<<<L1G_NB, 256, 0, stream>>>((const float4*)all_embed,
      (const float4*)m_rel, b_rel, (const float4*)wat, (const float4*)wbt,
      kg_off, t_list, r_list, list_gate, list_s1, counters, cnt, csr,
      (float4*)collab1, (float4*)x2);

  k_spmm2g<<<768, 256, 0, stream>>>(cnt, csr, x2, all_embed, collab1,
      user_ids, item_ids, user_e, item_e);
  dim3 grid_out(2048/64, 1024/64);
  k_out<<<grid_out, 256, 0, stream>>>(user_e, item_e, out);
}

// Round 10
// 183.723 us; speedup vs baseline: 1.8140x; 1.1280x over previous
//
#include <hip/hip_runtime.h>

#define N_ENT 100000
#define N_USR 30000
#define N_TOTN 130000
#define N_RELC 32
#define DIM 64
#define NEDGE 500000
#define INTER 500000
#define SLOPE 0.01f
#define CPT_NB 127     // compaction blocks: 127*1024 = 130048 >= 130000
#define FILL_NB 489    // ceil(125000/256) — 4 pairs per thread
#define MARK_NB 489
#define ATT_NB 512     // att+gate blocks (512 threads each) inside fused k_l1g
#define SP_NB 512      // spmm blocks inside fused k_l1g
#define RSTR 64        // fixed CSR row stride (max degree; Poisson(16.7) tail ~1e-16)
#define KGOFF_NB 1954  // ceil((NEDGE+1)/256)

typedef unsigned char u8;
typedef unsigned long long u64;

__device__ __forceinline__ float grp_sum16(float v){
  v += __shfl_xor(v, 8, 64);
  v += __shfl_xor(v, 4, 64);
  v += __shfl_xor(v, 2, 64);
  v += __shfl_xor(v, 1, 64);
  return v;
}

// fused: m_rel/b_rel (17) + r2 flags (12) + kg_off boundary scan (1954).
// NOTE: zero-init of cnt/counters/flags is a SEPARATE prior hipMemsetAsync —
// folding it in here raced with the r2-flag writes (R11 failure).
// NOTE 2: manual grid barriers / cooperative launch are CONDEMNED on this
// stack (R1 silent no-launch; R2/R3 HSA aborts). Regular launches only.
// NOTE 3: same-address global atomic work-stealing is CONDEMNED (R8: 16K
// single-address RMWs serialized ~150us). Static partitions only.
// NOTE 4: k_l1g structural search exhausted (R6=41us best; R7 LDS-free 43;
// R8 atomic pool 190; R9 wave-per-row 64). 41us ~= random-gather BW floor
// (43MB @ ~1TB/s effective, MSHR-limited).
__global__ void __launch_bounds__(256) k_prep(
    const float* __restrict__ rel, const float* __restrict__ Wk,
    const float* __restrict__ Wkb, float* __restrict__ m, float* __restrict__ b,
    const int* __restrict__ user_ids, const int* __restrict__ item_ids,
    u8* __restrict__ r2_item, u8* __restrict__ r2_user,
    const int* __restrict__ h_list, int* __restrict__ off){
  int bid = blockIdx.x;
  if (bid < 17){
    int idx = bid*256 + threadIdx.x;
    if (idx < N_RELC*128){
      int r = idx >> 7, j = idx & 127;
      float s = 0.f;
      for (int d = 0; d < DIM; ++d) s += rel[r*DIM+d] * Wk[d*128+j];
      m[idx] = s;
    } else if (idx < N_RELC*128 + N_RELC){
      int r = idx - N_RELC*128;
      float s = 0.f;
      for (int d = 0; d < DIM; ++d) s += Wkb[d] * rel[r*DIM+d];
      b[r] = s;
    }
  } else if (bid < 29){
    int i = (bid - 17)*256 + threadIdx.x;
    if (i < 1024) r2_user[user_ids[i] - N_ENT] = 1;
    else if (i < 3072) r2_item[item_ids[i - 1024]] = 1;
  } else {
    int e = (bid - 29)*256 + threadIdx.x;
    if (e <= NEDGE){
      int hc = (e < NEDGE) ? h_list[e] : N_ENT;
      int hp = (e == 0) ? -1 : h_list[e-1];
      for (int s = hp+1; s <= hc; ++s) off[s] = e;
    }
  }
}

// mark spmm-2 input columns (bipartite symmetry), 4 pairs per thread via int4
__global__ void k_mark(const int4* __restrict__ a_row4, const int4* __restrict__ a_col4,
                       const u8* __restrict__ r2_item, const u8* __restrict__ r2_user,
                       u8* __restrict__ need_d, u8* __restrict__ need_u){
  int i = blockIdx.x*256 + threadIdx.x;
  if (i >= INTER/4) return;
  int4 ar = a_row4[i];
  int4 ac = a_col4[i];
  #pragma unroll
  for (int k = 0; k < 4; ++k){
    int it = (&ar.x)[k];
    int uu = (&ac.x)[k] - N_ENT;
    if (r2_item[it]) need_u[uu] = 1;
    if (r2_user[uu]) need_d[it] = 1;
  }
}

// fused: list compaction (blocks < CPT_NB) + fixed-stride CSR fill (4 pairs/thread)
// Gated item rows (need_d) are EXCLUDED from list_s1 — their collab row is
// computed inside k_l1g's att branch (per-row gate fusion).
__global__ void __launch_bounds__(256) k_buildfill(
    const int* __restrict__ a_row, const int* __restrict__ a_col,
    const float* __restrict__ a_vals,
    const u8* __restrict__ need_d, const u8* __restrict__ need_u,
    const u8* __restrict__ r2_item, const u8* __restrict__ r2_user,
    int* __restrict__ list_gate, int* __restrict__ list_s1,
    int* __restrict__ counters, int* __restrict__ cnt, int2* __restrict__ csr){
  if (blockIdx.x < CPT_NB){
    __shared__ u64 mg_sh[16], ms_sh[16];
    __shared__ int pre_g[16], pre_s[16];
    __shared__ int base_sh[2];
    int t = threadIdx.x;
    int wave = t >> 6, lane = t & 63;
    bool pg[4], ps[4];
    int ibase = blockIdx.x*1024;
    #pragma unroll
    for (int k = 0; k < 4; ++k){
      int i = ibase + k*256 + t;
      bool g = false, s = false;
      if (i < N_TOTN){
        if (i < N_ENT){ g = need_d[i] != 0; s = (!g) && (r2_item[i] != 0); }
        else { int u = i - N_ENT; s = (need_u[u] != 0) || (r2_user[u] != 0); }
      }
      pg[k] = g; ps[k] = s;
      u64 mg = __ballot(g), ms = __ballot(s);
      if (lane == 0){ mg_sh[k*4 + wave] = mg; ms_sh[k*4 + wave] = ms; }
    }
    __syncthreads();
    if (t == 0){
      int sg = 0, ss = 0;
      for (int j = 0; j < 16; ++j){
        pre_g[j] = sg; sg += __popcll(mg_sh[j]);
        pre_s[j] = ss; ss += __popcll(ms_sh[j]);
      }
      base_sh[0] = sg ? atomicAdd(&counters[0], sg) : 0;
      base_sh[1] = ss ? atomicAdd(&counters[1], ss) : 0;
    }
    __syncthreads();
    int bg = base_sh[0], bs = base_sh[1];
    u64 lmask = (1ull << lane) - 1;
    #pragma unroll
    for (int k = 0; k < 4; ++k){
      int i = ibase + k*256 + t;
      if (pg[k]) list_gate[bg + pre_g[k*4+wave] + __popcll(mg_sh[k*4+wave] & lmask)] = i;
      if (ps[k]) list_s1 [bs + pre_s[k*4+wave] + __popcll(ms_sh[k*4+wave] & lmask)] = i;
    }
  } else {
    int i = (blockIdx.x - CPT_NB)*256 + threadIdx.x;
    if (i >= INTER/4) return;
    int4 ar = ((const int4*)a_row)[i];
    int4 ac = ((const int4*)a_col)[i];
    float4 av0 = ((const float4*)a_vals)[i];
    float4 av1 = ((const float4*)(a_vals + INTER))[i];
    #pragma unroll
    for (int k = 0; k < 4; ++k){
      int it = (&ar.x)[k];
      int uc = (&ac.x)[k];
      int uu = uc - N_ENT;
      if (need_d[it] | r2_item[it]){
        int p = atomicAdd(&cnt[it], 1);
        if (p < RSTR) csr[((size_t)it << 6) + p] = make_int2(uc, __float_as_int((&av0.x)[k]));
      }
      if (need_u[uu] | r2_user[uu]){
        int p = atomicAdd(&cnt[uc], 1);
        if (p < RSTR) csr[((size_t)uc << 6) + p] = make_int2(it, __float_as_int((&av1.x)[k]));
      }
    }
  }
}

// fused layer-1 + per-row gate. Best measured config (R6, 41us): LDS holds
// only WaT/WbT (33.3KB); m_rel read from global (16KB, L1-resident);
// 512-thr blocks, lb(512,8): 4 blocks/CU x 8 waves = 32 waves/CU.
// Uniform kk across a wave's 4 groups -> LDS broadcast (conflict-free;
// rotation variant CAUSED conflicts, R5).
__global__ void __launch_bounds__(512, 8) k_l1g(const float4* __restrict__ ent4,
    const float4* __restrict__ m4, const float* __restrict__ bvec,
    const float* __restrict__ Wa, const float* __restrict__ Wb,
    const int* __restrict__ off, const int* __restrict__ t_list,
    const int* __restrict__ r_list, const int* __restrict__ list_gate,
    const int* __restrict__ list_s1, const int* __restrict__ counters,
    const int* __restrict__ cnt, const int2* __restrict__ csr,
    float4* __restrict__ collab4, float4* __restrict__ x2_4){
  __shared__ float WaT[64][65];   // WaT[k][d] = Wa[d][k]
  __shared__ float WbT[64][65];
  int t = threadIdx.x;
  if (blockIdx.x < ATT_NB){
    for (int i = t; i < 64*64; i += 512){
      int d = i >> 6, k = i & 63;
      WaT[k][d] = Wa[i];
      WbT[k][d] = Wb[i];
    }
    __syncthreads();
    int n = counters[0];
    int sub = t & 15;
    int grp = (blockIdx.x*512 + t) >> 4;
    int ng = (ATT_NB*512) >> 4;
    for (int idx = grp; idx < n; idx += ng){
      int s = list_gate[idx];
      // --- attention -> kg (in-register) ---
      int beg = off[s], end = off[s+1];
      float4 h4 = ent4[(size_t)s*16 + sub];
      float l = 0.f;
      float4 acc = {0.f,0.f,0.f,0.f};
      for (int base = beg; base < end; base += 16){
        int mch = end - base; if (mch > 16) mch = 16;
        int tj = 0, rj = 0;
        if (sub < mch){ tj = t_list[base + sub]; rj = r_list[base + sub]; }
        #pragma unroll 4
        for (int j = 0; j < mch; ++j){
          int ti = __shfl(tj, j, 16);
          int r  = __shfl(rj, j, 16);
          float4 t4 = ent4[(size_t)ti*16 + sub];
          float4 mt = m4[r*32 + sub];        // m_rel: 16KB, L1-resident
          float4 mh = m4[r*32 + 16 + sub];
          float v = t4.x*mt.x + t4.y*mt.y + t4.z*mt.z + t4.w*mt.w
                  + h4.x*mh.x + h4.y*mh.y + h4.z*mh.z + h4.w*mh.w;
          v = grp_sum16(v) + bvec[r];
          v = (v >= 0.f) ? v : SLOPE * v;
          float w = __expf(v);
          l += w;
          acc.x += w*t4.x; acc.y += w*t4.y; acc.z += w*t4.z; acc.w += w*t4.w;
        }
      }
      float inv = (end > beg) ? 1.f / l : 0.f;
      float4 kg = {acc.x*inv, acc.y*inv, acc.z*inv, acc.w*inv};
      // --- this row's collab (CSR spmm, deg ~5 for items) ---
      int deg = cnt[s]; if (deg > RSTR) deg = RSTR;
      size_t base0 = (size_t)s << 6;
      float4 cb = {0.f,0.f,0.f,0.f};
      for (int b = 0; b < deg; b += 16){
        int mch = deg - b; if (mch > 16) mch = 16;
        int2 e = make_int2(0, 0);
        if (sub < mch) e = csr[base0 + b + sub];
        #pragma unroll 4
        for (int j = 0; j < mch; ++j){
          int cj = __shfl(e.x, j, 16);
          float vj = __int_as_float(__shfl(e.y, j, 16));
          float4 sv = ent4[(size_t)cj*16 + sub];
          cb.x += vj*sv.x; cb.y += vj*sv.y; cb.z += vj*sv.z; cb.w += vj*sv.w;
        }
      }
      // --- gate: ga[d] = sum_k kg[k]*Wa[d][k] + cb[k]*Wb[d][k] ---
      // uniform kk across the wave's 4 groups -> LDS broadcast (no rotation!)
      int d0 = sub*4;
      float4 ga = {0.f,0.f,0.f,0.f};
      for (int kk = 0; kk < 16; ++kk){
        float kqx = __shfl(kg.x, kk, 16), kqy = __shfl(kg.y, kk, 16);
        float kqz = __shfl(kg.z, kk, 16), kqw = __shfl(kg.w, kk, 16);
        float cqx = __shfl(cb.x, kk, 16), cqy = __shfl(cb.y, kk, 16);
        float cqz = __shfl(cb.z, kk, 16), cqw = __shfl(cb.w, kk, 16);
        int k0 = kk*4;
        #pragma unroll
        for (int j = 0; j < 4; ++j){
          float tsum = kqx*WaT[k0][d0+j] + kqy*WaT[k0+1][d0+j]
                     + kqz*WaT[k0+2][d0+j] + kqw*WaT[k0+3][d0+j]
                     + cqx*WbT[k0][d0+j] + cqy*WbT[k0+1][d0+j]
                     + cqz*WbT[k0+2][d0+j] + cqw*WbT[k0+3][d0+j];
          (&ga.x)[j] += tsum;
        }
      }
      float4 o;
      #pragma unroll
      for (int j = 0; j < 4; ++j){
        float g = 1.f / (1.f + __expf(-(&ga.x)[j]));
        (&o.x)[j] = g*(&kg.x)[j] + (1.f - g)*(&cb.x)[j];
      }
      collab4[(size_t)s*16 + sub] = cb;
      x2_4[(size_t)s*16 + sub] = o;
    }
  } else {
    int n = counters[1];
    int sub = t & 15;
    int bid = blockIdx.x - ATT_NB;
    int nb = gridDim.x - ATT_NB;
    int grp = (bid*512 + t) >> 4;
    int ng = (nb*512) >> 4;
    for (int idx = grp; idx < n; idx += ng){
      int i = list_s1[idx];
      int deg = cnt[i]; if (deg > RSTR) deg = RSTR;
      size_t base0 = (size_t)i << 6;
      float4 acc = {0.f,0.f,0.f,0.f};
      for (int b = 0; b < deg; b += 16){
        int mch = deg - b; if (mch > 16) mch = 16;
        int2 e = make_int2(0, 0);
        if (sub < mch) e = csr[base0 + b + sub];
        #pragma unroll 4
        for (int j = 0; j < mch; ++j){
          int cj = __shfl(e.x, j, 16);
          float vj = __int_as_float(__shfl(e.y, j, 16));
          float4 sv = ent4[(size_t)cj*16 + sub];   // src = all_embed table
          acc.x += vj*sv.x; acc.y += vj*sv.y; acc.z += vj*sv.z; acc.w += vj*sv.w;
        }
      }
      if (i < N_ENT) collab4[(size_t)i*16 + sub] = acc;
      else x2_4[(size_t)i*16 + sub] = acc;
    }
  }
}

// fused spmm-2 + gather: one 64-lane wave per output row, lane = dim.
__global__ void __launch_bounds__(256) k_spmm2g(const int* __restrict__ cnt,
    const int2* __restrict__ csr, const float* __restrict__ x2,
    const float* __restrict__ all_embed, const float* __restrict__ collab1,
    const int* __restrict__ user_ids, const int* __restrict__ item_ids,
    float* __restrict__ user_e, float* __restrict__ item_e){
  int lane = threadIdx.x & 63;
  int g = (blockIdx.x*256 + threadIdx.x) >> 6;
  if (g >= 3072) return;
  int id;
  float b1;
  if (g < 1024){
    id = user_ids[g];                            // >= N_ENT
    b1 = x2[(size_t)id*64 + lane];               // users1 lives in x2
  } else {
    id = item_ids[g - 1024];
    b1 = collab1[(size_t)id*64 + lane];
  }
  float acc = all_embed[(size_t)id*64 + lane] + b1;
  int deg = cnt[id]; if (deg > RSTR) deg = RSTR;
  size_t base0 = (size_t)id << 6;
  int2 e = make_int2(0, 0);
  if (lane < deg) e = csr[base0 + lane];
  #pragma unroll 8
  for (int j = 0; j < deg; ++j){
    int cj = __shfl(e.x, j, 64);
    float vj = __int_as_float(__shfl(e.y, j, 64));
    acc += vj * x2[(size_t)cj*64 + lane];
  }
  if (g < 1024) user_e[(size_t)g*64 + lane] = acc;
  else item_e[(size_t)(g - 1024)*64 + lane] = acc;
}

// out[1024][2048] = user_e @ item_e^T, 64x64 tiles, 4x4 micro-tile, K=64
__global__ void __launch_bounds__(256) k_out(const float* __restrict__ ue,
    const float* __restrict__ ie, float* __restrict__ out){
  __shared__ float ash[64][65];
  __shared__ float bsh[64][65];
  int row0 = blockIdx.y * 64, col0 = blockIdx.x * 64;
  for (int i = threadIdx.x; i < 64*64; i += 256){
    int r = i >> 6, c = i & 63;
    ash[r][c] = ue[(size_t)(row0 + r)*DIM + c];
    bsh[r][c] = ie[(size_t)(col0 + r)*DIM + c];
  }
  __syncthreads();
  int tx = threadIdx.x & 15, ty = threadIdx.x >> 4;
  int r0 = ty*4, c0 = tx*4;
  float acc[4][4] = {};
  #pragma unroll
  for (int k = 0; k < 64; ++k){
    float a0 = ash[r0][k], a1 = ash[r0+1][k], a2 = ash[r0+2][k], a3 = ash[r0+3][k];
    float b0 = bsh[c0][k], b1 = bsh[c0+1][k], b2 = bsh[c0+2][k], b3 = bsh[c0+3][k];
    acc[0][0] += a0*b0; acc[0][1] += a0*b1; acc[0][2] += a0*b2; acc[0][3] += a0*b3;
    acc[1][0] += a1*b0; acc[1][1] += a1*b1; acc[1][2] += a1*b2; acc[1][3] += a1*b3;
    acc[2][0] += a2*b0; acc[2][1] += a2*b1; acc[2][2] += a2*b2; acc[2][3] += a2*b3;
    acc[3][0] += a3*b0; acc[3][1] += a3*b1; acc[3][2] += a3*b2; acc[3][3] += a3*b3;
  }
  #pragma unroll
  for (int i = 0; i < 4; ++i){
    float4 o = {acc[i][0], acc[i][1], acc[i][2], acc[i][3]};
    *(float4*)&out[(size_t)(row0 + r0 + i)*2048 + col0 + c0] = o;
  }
}

extern "C" void kernel_launch(void* const* d_in, const int* in_sizes, int n_in,
                              void* d_out, int out_size, void* d_ws, size_t ws_size,
                              hipStream_t stream){
  const float* all_embed = (const float*)d_in[0];
  const float* rel_embed = (const float*)d_in[1];
  const float* Wk_w      = (const float*)d_in[2];
  const float* Wk_b      = (const float*)d_in[3];
  const float* Wa_w      = (const float*)d_in[4];
  const float* Wb_w      = (const float*)d_in[5];
  const float* a_vals    = (const float*)d_in[6];
  const int* user_ids   = (const int*)d_in[7];
  const int* item_ids   = (const int*)d_in[8];
  const int* h_list     = (const int*)d_in[9];
  const int* t_list     = (const int*)d_in[10];
  const int* r_list     = (const int*)d_in[11];
  const int* a_row      = (const int*)d_in[12];
  const int* a_col      = (const int*)d_in[13];
  float* out = (float*)d_out;

  char* p = (char*)d_ws;
  auto alloc = [&](size_t bytes)->void*{
    void* r = (void*)p;
    p += (bytes + 255) & ~(size_t)255;
    return r;
  };
  float* m_rel   = (float*)alloc((size_t)N_RELC*128*4);
  float* b_rel   = (float*)alloc((size_t)N_RELC*4);
  int*   kg_off  = (int*)  alloc((size_t)(N_ENT+1)*4);
  // zero region (separate memset BEFORE k_prep — do not fuse, see R11 race)
  size_t zbytes = (size_t)N_TOTN*4 + 256 + (2*(size_t)N_ENT + 2*(size_t)N_USR);
  char*  zbase  = (char*)alloc(zbytes);
  int*   cnt      = (int*)zbase;
  int*   counters = (int*)(zbase + (size_t)N_TOTN*4);   // [0]=gate n, [1]=s1 n
  u8*    r2_item  = (u8*)(zbase + (size_t)N_TOTN*4 + 256);
  u8*    r2_user  = r2_item + N_ENT;
  u8*    need_d   = r2_user + N_USR;
  u8*    need_u   = need_d + N_ENT;
  int2*  csr     = (int2*) alloc((size_t)N_TOTN*RSTR*8);
  int*   list_gate = (int*)alloc((size_t)N_ENT*4);
  int*   list_s1   = (int*)alloc((size_t)N_TOTN*4);
  float* collab1 = (float*)alloc((size_t)N_ENT*DIM*4);
  float* x2      = (float*)alloc((size_t)N_TOTN*DIM*4);  // [dual ; users1]
  float* user_e  = (float*)alloc((size_t)1024*DIM*4);
  float* item_e  = (float*)alloc((size_t)2048*DIM*4);

  hipMemsetAsync(zbase, 0, zbytes, stream);
  k_prep<<<29 + KGOFF_NB, 256, 0, stream>>>(rel_embed, Wk_w, Wk_b,
      m_rel, b_rel, user_ids, item_ids, r2_item, r2_user, h_list, kg_off);
  k_mark<<<MARK_NB, 256, 0, stream>>>((const int4*)a_row, (const int4*)a_col,
      r2_item, r2_user, need_d, need_u);
  k_buildfill<<<CPT_NB + FILL_NB, 256, 0, stream>>>(a_row, a_col, a_vals,
      need_d, need_u, r2_item, r2_user, list_gate, list_s1, counters, cnt, csr);
  // after k_buildfill: cnt[r] == deg(r) for needed rows, csr row r at [r*64, r*64+deg)

  k_l1g<<<ATT_NB + SP_NB, 512, 0, stream>>>((const float4*)all_embed,
      (const float4*)m_rel, b_rel, Wa_w, Wb_w, kg_off, t_list, r_list,
      list_gate, list_s1, counters, cnt, csr, (float4*)collab1, (float4*)x2);

  k_spmm2g<<<768, 256, 0, stream>>>(cnt, csr, x2, all_embed, collab1,
      user_ids, item_ids, user_e, item_e);
  dim3 grid_out(2048/64, 1024/64);
  k_out<<<grid_out, 256, 0, stream>>>(user_e, item_e, out);
}